// Round 4
// baseline (362.174 us; speedup 1.0000x reference)
//
#include <hip/hip_runtime.h>
#include <math.h>

#define B_  8
#define T_  2048
#define D_  1024
#define E_  8
#define FF_ 4096
#define N_  64            // B*E rows through the FFN
#define BT_ (B_*T_)
#define WGS 1028          // padded wgT stride (setup staging only)

// ---------------------------------------------------------------------------
// K1: logits[bt][e] = X[bt]·Wg[:,e] + bg[e]; sumexp[b][e] = sum_T exp(logit).
// Wg register-resident (128 VGPR); X direct-from-global coalesced.
// 512 blocks (2/CU) for latency hiding; 8 tokens per wave.
// ---------------------------------------------------------------------------
__global__ __launch_bounds__(256) void k_logits(
    const float* __restrict__ X, const float* __restrict__ Wg,
    const float* __restrict__ bg, float* __restrict__ logits,
    float* __restrict__ sumexp)
{
    __shared__ float wgT[E_ * WGS];   // 32.9 KB, setup only

    const int tid  = threadIdx.x;
    const int lane = tid & 63;
    const int wv   = tid >> 6;

    #pragma unroll
    for (int r = 0; r < 32; ++r) {
        int idx = r * 256 + tid;               // idx = d*8 + e
        wgT[(idx & 7) * WGS + (idx >> 3)] = Wg[idx];
    }
    __syncthreads();

    float4 w4[4][8];
    #pragma unroll
    for (int j = 0; j < 4; ++j)
        #pragma unroll
        for (int e = 0; e < 8; ++e)
            w4[j][e] = *(const float4*)&wgT[e * WGS + j * 256 + lane * 4];

    const int t0 = blockIdx.x * 32 + wv * 8;    // 8 tokens per wave
    const int b  = t0 >> 11;
    const float bgv = bg[lane & 7];

    float se = 0.f;
    const float* xrow = &X[(size_t)t0 * D_ + lane * 4];

    float4 xc[4];
    #pragma unroll
    for (int j = 0; j < 4; ++j) xc[j] = *(const float4*)&xrow[j * 256];

    for (int t = 0; t < 8; ++t) {
        float4 xn[4];
        if (t < 7) {
            #pragma unroll
            for (int j = 0; j < 4; ++j)
                xn[j] = *(const float4*)&xrow[(size_t)(t + 1) * D_ + j * 256];
        }
        float acc[8];
        #pragma unroll
        for (int e = 0; e < 8; ++e) acc[e] = 0.f;
        #pragma unroll
        for (int j = 0; j < 4; ++j) {
            const float4 x = xc[j];
            #pragma unroll
            for (int e = 0; e < 8; ++e) {
                const float4 w = w4[j][e];
                acc[e] += x.x * w.x + x.y * w.y + x.z * w.z + x.w * w.w;
            }
        }
        #pragma unroll
        for (int j = 0; j < 4; ++j) xc[j] = xn[j];

        #pragma unroll
        for (int e = 0; e < 8; ++e) {
            acc[e] += __shfl_xor(acc[e], 1);
            acc[e] += __shfl_xor(acc[e], 2);
            acc[e] += __shfl_xor(acc[e], 4);
        }
        const float a01 = (lane & 1) ? acc[1] : acc[0];
        const float a23 = (lane & 1) ? acc[3] : acc[2];
        const float a45 = (lane & 1) ? acc[5] : acc[4];
        const float a67 = (lane & 1) ? acc[7] : acc[6];
        const float a03 = (lane & 2) ? a23 : a01;
        const float a47 = (lane & 2) ? a67 : a45;
        float v = (lane & 4) ? a47 : a03;
        v += __shfl_xor(v, 8);
        v += __shfl_xor(v, 16);
        v += __shfl_xor(v, 32);
        v += bgv;
        if (lane < 8) logits[(size_t)(t0 + t) * E_ + lane] = v;
        se += __expf(v);
    }
    if (lane < 8) atomicAdd(&sumexp[b * E_ + lane], se);
}

// ---------------------------------------------------------------------------
// K2: dispatch weights dw[b][t][e] = exp(logit)/sumexp[b][e].  512 x 256.
// ---------------------------------------------------------------------------
__global__ __launch_bounds__(256) void k_dispatch(
    const float* __restrict__ logits, const float* __restrict__ sumexp,
    float* __restrict__ dw)
{
    const int idx = blockIdx.x * 256 + threadIdx.x;   // 131072
    const int e = idx & 7, b = idx >> 14;
    dw[idx] = __expf(logits[idx]) / sumexp[b * E_ + e];
}

// ---------------------------------------------------------------------------
// K3: slots[b*8+e][d] = sum_t dw[b][t][e] * X[b][t][d]  — fused, no partials.
// Grid (32 d-chunks, 8 b) = 256 blocks. X read exactly once (64 MB).
// dw chunk staged transposed [e][t] in LDS (broadcast reads, imm offsets).
// Lane = (t_sub 0..7, d4 0..7): float4 of X per lane; butterfly + LDS reduce.
// ---------------------------------------------------------------------------
__global__ __launch_bounds__(256) void k_slots(
    const float* __restrict__ X, const float* __restrict__ dw,
    float* __restrict__ slots)
{
    __shared__ float dwl[E_ * 516];        // [e][t-chunk 512], stride 516 (free banks)
    __shared__ float4 red4[4 * 64];        // cross-wave reduce: [wv][e*8+d4]

    const int tid  = threadIdx.x;
    const int lane = tid & 63;
    const int wv   = tid >> 6;
    const int t_sub = lane >> 3;
    const int d4    = lane & 7;
    const int d0 = blockIdx.x * 32;
    const int b  = blockIdx.y;

    float4 acc[8];
    #pragma unroll
    for (int e = 0; e < 8; ++e) { acc[e].x = acc[e].y = acc[e].z = acc[e].w = 0.f; }

    const float* xp = &X[((size_t)b * T_ + wv * 8 + t_sub) * D_ + d0 + d4 * 4];
    const float* dwg = &dw[(size_t)b * T_ * E_];

    for (int p = 0; p < 4; ++p) {                  // 4 phases x 512 tokens
        __syncthreads();
        // stage dw[b][p*512 + t][e] -> dwl[e][t] (transposed)
        #pragma unroll
        for (int r = 0; r < 4; ++r) {
            const int i4 = r * 256 + tid;          // float4 index within 4096 elems
            const float4 v = *(const float4*)&dwg[(size_t)p * 4096 + i4 * 4];
            const int t = i4 >> 1, e0 = (i4 & 1) * 4;
            dwl[(e0 + 0) * 516 + t] = v.x;
            dwl[(e0 + 1) * 516 + t] = v.y;
            dwl[(e0 + 2) * 516 + t] = v.z;
            dwl[(e0 + 3) * 516 + t] = v.w;
        }
        __syncthreads();

        #pragma unroll 8
        for (int it = 0; it < 16; ++it) {
            const int tl = wv * 8 + t_sub + it * 32;            // 0..511
            const float4 x = *(const float4*)&xp[((size_t)p * 512 + it * 32) * D_];
            #pragma unroll
            for (int e = 0; e < 8; ++e) {
                const float w = dwl[e * 516 + tl];              // broadcast x8
                acc[e].x += w * x.x; acc[e].y += w * x.y;
                acc[e].z += w * x.z; acc[e].w += w * x.w;
            }
        }
    }

    // reduce across t_sub (lane bits 3..5)
    #pragma unroll
    for (int e = 0; e < 8; ++e) {
        #pragma unroll
        for (int m = 8; m <= 32; m <<= 1) {
            acc[e].x += __shfl_xor(acc[e].x, m);
            acc[e].y += __shfl_xor(acc[e].y, m);
            acc[e].z += __shfl_xor(acc[e].z, m);
            acc[e].w += __shfl_xor(acc[e].w, m);
        }
    }
    if (t_sub == 0) {
        #pragma unroll
        for (int e = 0; e < 8; ++e) red4[wv * 64 + e * 8 + d4] = acc[e];
    }
    __syncthreads();
    if (tid < 64) {
        const int e = tid >> 3, dd = tid & 7;
        float4 s = red4[e * 8 + dd];
        #pragma unroll
        for (int w = 1; w < 4; ++w) {
            const float4 r = red4[w * 64 + e * 8 + dd];
            s.x += r.x; s.y += r.y; s.z += r.z; s.w += r.w;
        }
        *(float4*)&slots[(size_t)(b * E_ + e) * D_ + d0 + dd * 4] = s;
    }
}

// ---------------------------------------------------------------------------
// K4/K6: k-split GEMM, no LDS in hot loop. W-fragment in VGPRs (KR per
// thread); A rows read via wave-uniform loads (L1-resident chunk).
// grid (FTOT/FB, KTOT/KR); 256 thr = FB f-lanes x NSPL n-groups.
// ---------------------------------------------------------------------------
template<int KTOT, int FTOT, int KR, int FB, int NSPL>
__global__ __launch_bounds__(256) void k_gemm(
    const float* __restrict__ A, const float* __restrict__ W,
    float* __restrict__ part)
{
    const int tid = threadIdx.x;
    const int fi = tid % FB;
    const int f  = blockIdx.x * FB + fi;
    const int k0 = blockIdx.y * KR;
    constexpr int NR = 64 / NSPL;
    const int nbase = __builtin_amdgcn_readfirstlane((tid / FB) * NR);

    float w[KR];
    #pragma unroll
    for (int kk = 0; kk < KR; ++kk)
        w[kk] = W[(size_t)(k0 + kk) * FTOT + f];

    float acc[NR];
    #pragma unroll
    for (int j = 0; j < NR; ++j) acc[j] = 0.f;

    #pragma unroll 4
    for (int j = 0; j < NR; ++j) {
        const float* ar = &A[(size_t)(nbase + j) * KTOT + k0];  // wave-uniform
        float a = 0.f; (void)a;
        #pragma unroll
        for (int k4 = 0; k4 < KR / 4; ++k4) {
            const float4 av = *(const float4*)&ar[k4 * 4];
            acc[j] += av.x * w[k4*4+0] + av.y * w[k4*4+1]
                    + av.z * w[k4*4+2] + av.w * w[k4*4+3];
        }
    }

    const size_t base = (size_t)blockIdx.y * N_ * FTOT;
    #pragma unroll
    for (int j = 0; j < NR; ++j)
        part[base + (size_t)(nbase + j) * FTOT + f] = acc[j];
}

// K5: reduce 16 GEMM1 partials + b1 + SiLU -> h[64][4096]
__global__ __launch_bounds__(256) void k_reduce_silu(
    const float* __restrict__ part, const float* __restrict__ b1,
    float* __restrict__ h)
{
    const int i = blockIdx.x * 256 + threadIdx.x;     // 262144
    float s = 0.f;
    #pragma unroll
    for (int p = 0; p < 16; ++p) s += part[(size_t)p * (N_ * FF_) + i];
    s += b1[i & (FF_ - 1)];
    h[i] = s / (1.f + __expf(-s));
}

// K7: reduce 32 GEMM2 partials + b2 -> y[64][1024]
__global__ __launch_bounds__(256) void k_reduce_bias(
    const float* __restrict__ part, const float* __restrict__ b2,
    float* __restrict__ y)
{
    const int i = blockIdx.x * 256 + threadIdx.x;     // 65536
    float s = 0.f;
    #pragma unroll
    for (int p = 0; p < 32; ++p) s += part[(size_t)p * (N_ * D_) + i];
    y[i] = s + b2[i & (D_ - 1)];
}

// ---------------------------------------------------------------------------
// K8: out[b][t][d] = sum_e softmax_e(logits)[e] * y[b*8+e][d]
//     Grid (64 tc, 8 b) = 512 blocks; thread owns 4 d (float4 stores).
// ---------------------------------------------------------------------------
__global__ __launch_bounds__(256) void k_combine(
    const float* __restrict__ logits, const float* __restrict__ y,
    float* __restrict__ out)
{
    __shared__ float wlds[32 * 8];
    const int tid = threadIdx.x;
    const int tc = blockIdx.x, b = blockIdx.y;
    const int t0 = tc * 32;

    if (tid < 32) {
        const float* lp = &logits[((size_t)b * T_ + t0 + tid) * E_];
        float ex[8]; float s = 0.f;
        #pragma unroll
        for (int i = 0; i < 8; ++i) { ex[i] = __expf(lp[i]); s += ex[i]; }
        const float invs = 1.f / s;
        #pragma unroll
        for (int i = 0; i < 8; ++i) wlds[tid * 8 + i] = ex[i] * invs;
    }
    __syncthreads();

    float4 yv[8];
    #pragma unroll
    for (int e = 0; e < 8; ++e)
        yv[e] = *(const float4*)&y[(size_t)(b * E_ + e) * D_ + tid * 4];

    #pragma unroll 4
    for (int t = 0; t < 32; ++t) {
        const float4 wA = *(const float4*)&wlds[t * 8];
        const float4 wB = *(const float4*)&wlds[t * 8 + 4];
        float4 a;
        a.x = wA.x*yv[0].x + wA.y*yv[1].x + wA.z*yv[2].x + wA.w*yv[3].x
            + wB.x*yv[4].x + wB.y*yv[5].x + wB.z*yv[6].x + wB.w*yv[7].x;
        a.y = wA.x*yv[0].y + wA.y*yv[1].y + wA.z*yv[2].y + wA.w*yv[3].y
            + wB.x*yv[4].y + wB.y*yv[5].y + wB.z*yv[6].y + wB.w*yv[7].y;
        a.z = wA.x*yv[0].z + wA.y*yv[1].z + wA.z*yv[2].z + wA.w*yv[3].z
            + wB.x*yv[4].z + wB.y*yv[5].z + wB.z*yv[6].z + wB.w*yv[7].z;
        a.w = wA.x*yv[0].w + wA.y*yv[1].w + wA.z*yv[2].w + wA.w*yv[3].w
            + wB.x*yv[4].w + wB.y*yv[5].w + wB.z*yv[6].w + wB.w*yv[7].w;
        *(float4*)&out[((size_t)b * T_ + t0 + t) * D_ + tid * 4] = a;
    }
}

// ---------------------------------------------------------------------------
extern "C" void kernel_launch(void* const* d_in, const int* in_sizes, int n_in,
                              void* d_out, int out_size, void* d_ws, size_t ws_size,
                              hipStream_t stream)
{
    const float* X  = (const float*)d_in[0];
    const float* Wg = (const float*)d_in[1];
    const float* bg = (const float*)d_in[2];
    const float* W1 = (const float*)d_in[3];
    const float* b1 = (const float*)d_in[4];
    const float* W2 = (const float*)d_in[5];
    const float* b2 = (const float*)d_in[6];
    float* out = (float*)d_out;

    // ws layout (fp32), ~2.6 MB
    float* wsf    = (float*)d_ws;
    float* logits = wsf;                        // 131072
    float* sumexp = logits + BT_ * E_;          // 64
    float* slots  = sumexp + 64;                // 65536
    float* h      = slots + N_ * D_;            // 262144
    float* y      = h + N_ * FF_;               // 65536
    float* dwbuf  = y + N_ * D_;                // 131072

    // GEMM partials live in d_out (64 MB): gemm1 16 MB, gemm2 8 MB — both
    // dead before k_combine overwrites out.
    float* part = out;

    hipMemsetAsync(sumexp, 0, 64 * sizeof(float), stream);

    hipLaunchKernelGGL(k_logits,   dim3(BT_ / 32), dim3(256), 0, stream,
                       X, Wg, bg, logits, sumexp);
    hipLaunchKernelGGL(k_dispatch, dim3(BT_ * E_ / 256), dim3(256), 0, stream,
                       logits, sumexp, dwbuf);
    hipLaunchKernelGGL(k_slots,    dim3(32, 8), dim3(256), 0, stream,
                       X, dwbuf, slots);
    hipLaunchKernelGGL(HIP_KERNEL_NAME(k_gemm<1024, 4096, 64, 256, 1>),
                       dim3(4096 / 256, 1024 / 64), dim3(256), 0, stream,
                       slots, W1, part);
    hipLaunchKernelGGL(k_reduce_silu, dim3(N_ * FF_ / 256), dim3(256), 0, stream,
                       part, b1, h);
    hipLaunchKernelGGL(HIP_KERNEL_NAME(k_gemm<4096, 1024, 128, 128, 2>),
                       dim3(1024 / 128, 4096 / 128), dim3(256), 0, stream,
                       h, W2, part);
    hipLaunchKernelGGL(k_reduce_bias, dim3(N_ * D_ / 256), dim3(256), 0, stream,
                       part, b2, y);
    hipLaunchKernelGGL(k_combine,  dim3(64, 8), dim3(256), 0, stream,
                       logits, y, out);
}

// Round 5
// 283.937 us; speedup vs baseline: 1.2755x; 1.2755x over previous
//
#include <hip/hip_runtime.h>
#include <math.h>

#define B_  8
#define T_  2048
#define D_  1024
#define E_  8
#define FF_ 4096
#define N_  64            // B*E rows through the FFN
#define BT_ (B_*T_)
#define WGS 1028          // padded wgT stride (setup staging only)

// ---------------------------------------------------------------------------
// K1: logits[bt][e] = X[bt]·Wg[:,e] + bg[e]; sumexp[b][e] = sum_T exp(logit).
// Wg register-resident (128 VGPR); X direct-from-global coalesced.
// 512 blocks (2/CU); 8 tokens per wave; no LDS in hot loop.
// ---------------------------------------------------------------------------
__global__ __launch_bounds__(256) void k_logits(
    const float* __restrict__ X, const float* __restrict__ Wg,
    const float* __restrict__ bg, float* __restrict__ logits,
    float* __restrict__ sumexp)
{
    __shared__ float wgT[E_ * WGS];   // 32.9 KB, setup only

    const int tid  = threadIdx.x;
    const int lane = tid & 63;
    const int wv   = tid >> 6;

    #pragma unroll
    for (int r = 0; r < 32; ++r) {
        int idx = r * 256 + tid;               // idx = d*8 + e
        wgT[(idx & 7) * WGS + (idx >> 3)] = Wg[idx];
    }
    __syncthreads();

    float4 w4[4][8];
    #pragma unroll
    for (int j = 0; j < 4; ++j)
        #pragma unroll
        for (int e = 0; e < 8; ++e)
            w4[j][e] = *(const float4*)&wgT[e * WGS + j * 256 + lane * 4];

    const int t0 = blockIdx.x * 32 + wv * 8;    // 8 tokens per wave
    const int b  = t0 >> 11;
    const float bgv = bg[lane & 7];

    float se = 0.f;
    const float* xrow = &X[(size_t)t0 * D_ + lane * 4];

    float4 xc[4];
    #pragma unroll
    for (int j = 0; j < 4; ++j) xc[j] = *(const float4*)&xrow[j * 256];

    for (int t = 0; t < 8; ++t) {
        float4 xn[4];
        if (t < 7) {
            #pragma unroll
            for (int j = 0; j < 4; ++j)
                xn[j] = *(const float4*)&xrow[(size_t)(t + 1) * D_ + j * 256];
        }
        float acc[8];
        #pragma unroll
        for (int e = 0; e < 8; ++e) acc[e] = 0.f;
        #pragma unroll
        for (int j = 0; j < 4; ++j) {
            const float4 x = xc[j];
            #pragma unroll
            for (int e = 0; e < 8; ++e) {
                const float4 w = w4[j][e];
                acc[e] += x.x * w.x + x.y * w.y + x.z * w.z + x.w * w.w;
            }
        }
        #pragma unroll
        for (int j = 0; j < 4; ++j) xc[j] = xn[j];

        #pragma unroll
        for (int e = 0; e < 8; ++e) {
            acc[e] += __shfl_xor(acc[e], 1);
            acc[e] += __shfl_xor(acc[e], 2);
            acc[e] += __shfl_xor(acc[e], 4);
        }
        const float a01 = (lane & 1) ? acc[1] : acc[0];
        const float a23 = (lane & 1) ? acc[3] : acc[2];
        const float a45 = (lane & 1) ? acc[5] : acc[4];
        const float a67 = (lane & 1) ? acc[7] : acc[6];
        const float a03 = (lane & 2) ? a23 : a01;
        const float a47 = (lane & 2) ? a67 : a45;
        float v = (lane & 4) ? a47 : a03;
        v += __shfl_xor(v, 8);
        v += __shfl_xor(v, 16);
        v += __shfl_xor(v, 32);
        v += bgv;
        if (lane < 8) logits[(size_t)(t0 + t) * E_ + lane] = v;
        se += __expf(v);
    }
    if (lane < 8) atomicAdd(&sumexp[b * E_ + lane], se);
}

// ---------------------------------------------------------------------------
// K2: slots fused: slots[b*8+e][d] = (sum_t exp(l[b,t,e]) X[b,t,d]) / Z[b,e].
// exp applied during LDS staging; divide-by-Z in epilogue -> no dispatch-w
// buffer, no separate kernel. Grid (32 d-chunks, 8 b); X read exactly once.
// ---------------------------------------------------------------------------
__global__ __launch_bounds__(256) void k_slots(
    const float* __restrict__ X, const float* __restrict__ logits,
    const float* __restrict__ sumexp, float* __restrict__ slots)
{
    __shared__ float dwl[E_ * 516];        // [e][t-chunk 512] transposed
    __shared__ float4 red4[4 * 64];        // cross-wave reduce: [wv][e*8+d4]

    const int tid  = threadIdx.x;
    const int lane = tid & 63;
    const int wv   = tid >> 6;
    const int t_sub = lane >> 3;
    const int d4    = lane & 7;
    const int d0 = blockIdx.x * 32;
    const int b  = blockIdx.y;

    float4 acc[8];
    #pragma unroll
    for (int e = 0; e < 8; ++e) { acc[e].x = acc[e].y = acc[e].z = acc[e].w = 0.f; }

    const float* xp = &X[((size_t)b * T_ + wv * 8 + t_sub) * D_ + d0 + d4 * 4];
    const float* lg = &logits[(size_t)b * T_ * E_];

    for (int p = 0; p < 4; ++p) {                  // 4 phases x 512 tokens
        __syncthreads();
        #pragma unroll
        for (int r = 0; r < 4; ++r) {
            const int i4 = r * 256 + tid;          // float4 idx within 4096 elems
            const float4 v = *(const float4*)&lg[(size_t)p * 4096 + i4 * 4];
            const int t = i4 >> 1, e0 = (i4 & 1) * 4;
            dwl[(e0 + 0) * 516 + t] = __expf(v.x);
            dwl[(e0 + 1) * 516 + t] = __expf(v.y);
            dwl[(e0 + 2) * 516 + t] = __expf(v.z);
            dwl[(e0 + 3) * 516 + t] = __expf(v.w);
        }
        __syncthreads();

        #pragma unroll 8
        for (int it = 0; it < 16; ++it) {
            const int tl = wv * 8 + t_sub + it * 32;            // 0..511
            const float4 x = *(const float4*)&xp[((size_t)p * 512 + it * 32) * D_];
            #pragma unroll
            for (int e = 0; e < 8; ++e) {
                const float w = dwl[e * 516 + tl];              // broadcast
                acc[e].x += w * x.x; acc[e].y += w * x.y;
                acc[e].z += w * x.z; acc[e].w += w * x.w;
            }
        }
    }

    #pragma unroll
    for (int e = 0; e < 8; ++e) {
        #pragma unroll
        for (int m = 8; m <= 32; m <<= 1) {
            acc[e].x += __shfl_xor(acc[e].x, m);
            acc[e].y += __shfl_xor(acc[e].y, m);
            acc[e].z += __shfl_xor(acc[e].z, m);
            acc[e].w += __shfl_xor(acc[e].w, m);
        }
    }
    if (t_sub == 0) {
        #pragma unroll
        for (int e = 0; e < 8; ++e) red4[wv * 64 + e * 8 + d4] = acc[e];
    }
    __syncthreads();
    if (tid < 64) {
        const int e = tid >> 3, dd = tid & 7;
        const float invz = 1.f / sumexp[b * E_ + e];
        float4 s = red4[e * 8 + dd];
        #pragma unroll
        for (int w = 1; w < 4; ++w) {
            const float4 r = red4[w * 64 + e * 8 + dd];
            s.x += r.x; s.y += r.y; s.z += r.z; s.w += r.w;
        }
        s.x *= invz; s.y *= invz; s.z *= invz; s.w *= invz;
        *(float4*)&slots[(size_t)(b * E_ + e) * D_ + d0 + dd * 4] = s;
    }
}

// ---------------------------------------------------------------------------
// K3/K5: k-split GEMM partial (round-2 proven structure): LDS-staged A^T,
// 2 f-cols x 64 rows per thread in registers, broadcast LDS reads.
// grid.x = F/512 f-chunks, grid.y = K/32 k-chunks.
// ---------------------------------------------------------------------------
__global__ __launch_bounds__(256) void k_gemm_part(
    const float* __restrict__ A, const float* __restrict__ W,
    float* __restrict__ part, int K, int F)
{
    __shared__ float sT[32 * 68];                 // [kk][n], pad 68

    const int tid = threadIdx.x;
    const int f0 = blockIdx.x * 512 + tid;
    const int k0 = blockIdx.y * 32;

    #pragma unroll
    for (int r = 0; r < 8; ++r) {
        int idx = r * 256 + tid;
        int n = idx >> 5, kk = idx & 31;
        sT[kk * 68 + n] = A[(size_t)n * K + k0 + kk];
    }
    __syncthreads();

    float acc0[64], acc1[64];
    #pragma unroll
    for (int n = 0; n < 64; ++n) { acc0[n] = 0.f; acc1[n] = 0.f; }

    #pragma unroll 8
    for (int kk = 0; kk < 32; ++kk) {
        const float w0 = W[(size_t)(k0 + kk) * F + f0];
        const float w1 = W[(size_t)(k0 + kk) * F + f0 + 256];
        const float4* sp = (const float4*)&sT[kk * 68];   // broadcast reads
        #pragma unroll
        for (int j = 0; j < 16; ++j) {
            const float4 s = sp[j];
            acc0[4*j+0] += s.x * w0; acc0[4*j+1] += s.y * w0;
            acc0[4*j+2] += s.z * w0; acc0[4*j+3] += s.w * w0;
            acc1[4*j+0] += s.x * w1; acc1[4*j+1] += s.y * w1;
            acc1[4*j+2] += s.z * w1; acc1[4*j+3] += s.w * w1;
        }
    }

    const size_t base = (size_t)blockIdx.y * N_ * F;
    #pragma unroll
    for (int n = 0; n < 64; ++n) {
        part[base + (size_t)n * F + f0]       = acc0[n];
        part[base + (size_t)n * F + f0 + 256] = acc1[n];
    }
}

// K4: reduce 32 GEMM1 partials + b1 + SiLU -> h[64][4096]
__global__ __launch_bounds__(256) void k_reduce_silu(
    const float* __restrict__ part, const float* __restrict__ b1,
    float* __restrict__ h)
{
    const int i = blockIdx.x * 256 + threadIdx.x;     // 262144
    float s = 0.f;
    #pragma unroll
    for (int p = 0; p < 32; ++p) s += part[(size_t)p * (N_ * FF_) + i];
    s += b1[i & (FF_ - 1)];
    h[i] = s / (1.f + __expf(-s));
}

// K6: reduce 128 GEMM2 partials + b2 -> y[64][1024]
__global__ __launch_bounds__(256) void k_reduce_bias(
    const float* __restrict__ part, const float* __restrict__ b2,
    float* __restrict__ y)
{
    const int i = blockIdx.x * 256 + threadIdx.x;     // 65536
    float s = 0.f;
    #pragma unroll
    for (int p = 0; p < 128; ++p) s += part[(size_t)p * (N_ * D_) + i];
    y[i] = s + b2[i & (D_ - 1)];
}

// ---------------------------------------------------------------------------
// K7: out[b][t][d] = sum_e softmax_e(logits)[e] * y[b*8+e][d]
//     Grid (64 tc, 8 b) = 512 blocks; thread owns 4 d (float4 stores).
// ---------------------------------------------------------------------------
__global__ __launch_bounds__(256) void k_combine(
    const float* __restrict__ logits, const float* __restrict__ y,
    float* __restrict__ out)
{
    __shared__ float wlds[32 * 8];
    const int tid = threadIdx.x;
    const int tc = blockIdx.x, b = blockIdx.y;
    const int t0 = tc * 32;

    if (tid < 32) {
        const float* lp = &logits[((size_t)b * T_ + t0 + tid) * E_];
        float ex[8]; float s = 0.f;
        #pragma unroll
        for (int i = 0; i < 8; ++i) { ex[i] = __expf(lp[i]); s += ex[i]; }
        const float invs = 1.f / s;
        #pragma unroll
        for (int i = 0; i < 8; ++i) wlds[tid * 8 + i] = ex[i] * invs;
    }
    __syncthreads();

    float4 yv[8];
    #pragma unroll
    for (int e = 0; e < 8; ++e)
        yv[e] = *(const float4*)&y[(size_t)(b * E_ + e) * D_ + tid * 4];

    #pragma unroll 4
    for (int t = 0; t < 32; ++t) {
        const float4 wA = *(const float4*)&wlds[t * 8];
        const float4 wB = *(const float4*)&wlds[t * 8 + 4];
        float4 a;
        a.x = wA.x*yv[0].x + wA.y*yv[1].x + wA.z*yv[2].x + wA.w*yv[3].x
            + wB.x*yv[4].x + wB.y*yv[5].x + wB.z*yv[6].x + wB.w*yv[7].x;
        a.y = wA.x*yv[0].y + wA.y*yv[1].y + wA.z*yv[2].y + wA.w*yv[3].y
            + wB.x*yv[4].y + wB.y*yv[5].y + wB.z*yv[6].y + wB.w*yv[7].y;
        a.z = wA.x*yv[0].z + wA.y*yv[1].z + wA.z*yv[2].z + wA.w*yv[3].z
            + wB.x*yv[4].z + wB.y*yv[5].z + wB.z*yv[6].z + wB.w*yv[7].z;
        a.w = wA.x*yv[0].w + wA.y*yv[1].w + wA.z*yv[2].w + wA.w*yv[3].w
            + wB.x*yv[4].w + wB.y*yv[5].w + wB.z*yv[6].w + wB.w*yv[7].w;
        *(float4*)&out[((size_t)b * T_ + t0 + t) * D_ + tid * 4] = a;
    }
}

// ---------------------------------------------------------------------------
extern "C" void kernel_launch(void* const* d_in, const int* in_sizes, int n_in,
                              void* d_out, int out_size, void* d_ws, size_t ws_size,
                              hipStream_t stream)
{
    const float* X  = (const float*)d_in[0];
    const float* Wg = (const float*)d_in[1];
    const float* bg = (const float*)d_in[2];
    const float* W1 = (const float*)d_in[3];
    const float* b1 = (const float*)d_in[4];
    const float* W2 = (const float*)d_in[5];
    const float* b2 = (const float*)d_in[6];
    float* out = (float*)d_out;

    // ws layout (fp32), ~2.1 MB
    float* wsf    = (float*)d_ws;
    float* logits = wsf;                        // 131072
    float* sumexp = logits + BT_ * E_;          // 64
    float* slots  = sumexp + 64;                // 65536
    float* h      = slots + N_ * D_;            // 262144
    float* y      = h + N_ * FF_;               // 65536

    // GEMM partials live in d_out (64 MB): gemm1 32 MB, gemm2 32 MB — both
    // dead before k_combine overwrites out.
    float* part = out;

    hipMemsetAsync(sumexp, 0, 64 * sizeof(float), stream);

    hipLaunchKernelGGL(k_logits,   dim3(BT_ / 32), dim3(256), 0, stream,
                       X, Wg, bg, logits, sumexp);
    hipLaunchKernelGGL(k_slots,    dim3(32, 8), dim3(256), 0, stream,
                       X, logits, sumexp, slots);
    hipLaunchKernelGGL(k_gemm_part, dim3(FF_ / 512, 1024 / 32), dim3(256), 0, stream,
                       slots, W1, part, 1024, FF_);
    hipLaunchKernelGGL(k_reduce_silu, dim3(N_ * FF_ / 256), dim3(256), 0, stream,
                       part, b1, h);
    hipLaunchKernelGGL(k_gemm_part, dim3(D_ / 512, FF_ / 32), dim3(256), 0, stream,
                       h, W2, part, 4096, D_);
    hipLaunchKernelGGL(k_reduce_bias, dim3(N_ * D_ / 256), dim3(256), 0, stream,
                       part, b2, y);
    hipLaunchKernelGGL(k_combine,  dim3(64, 8), dim3(256), 0, stream,
                       logits, y, out);
}